// Round 1
// baseline (183.373 us; speedup 1.0000x reference)
//
#include <hip/hip_runtime.h>
#include <math.h>

// MovingZScoreNorm: x[32,8192,128] f32, W=24 (TF SAME avg-pool mean w/ valid
// counts; variance = windowed sum of per-row channel-summed sq / (W-1)).
//
// One wave per (batch, 64-row tile). Lane owns 2 channels (float2).
// Streaming over s with two running window sums (lead for sq_tot, trail for
// output mean), wave butterfly reduce for sq_tot, LDS ring (depth 64) so the
// variance window reads sq_tot values produced 12 iters earlier (slack for
// the shuffle chain). Output lagged 12 steps so all row reads are at offsets
// {+24,+12,0,-12,-24} of the loop var (1 fresh HBM row + 4 cache re-reads).

constexpr int Sdim = 8192;
constexpr int Cdim = 128;
constexpr int Ttile = 64;              // output rows per wave
constexpr float EPSv = 1e-7f;

__device__ __forceinline__ float2 ldx(const float* __restrict__ base, int t) {
    float2 v = make_float2(0.f, 0.f);
    if ((unsigned)t < (unsigned)Sdim)
        v = *reinterpret_cast<const float2*>(base + (size_t)t * Cdim);
    return v;
}

__device__ __forceinline__ float wave_sum(float v) {
#pragma unroll
    for (int m = 1; m < 64; m <<= 1)
        v += __shfl_xor(v, m, 64);
    return v;
}

__global__ __launch_bounds__(256, 4)
void mzs_kernel(const float* __restrict__ x, float* __restrict__ y) {
    __shared__ float ring[4][64];      // per-wave sq_tot ring, pos & 63
    const int tid  = threadIdx.x;
    const int lane = tid & 63;
    const int w    = tid >> 6;
    ring[w][lane] = 0.f;               // same-wave init, ordered before reads

    const int tile = blockIdx.x * 4 + w;        // 4096 tiles total
    const int b    = tile >> 7;                 // 128 tiles per batch
    const int t0   = (tile & 127) * Ttile;
    const int t1   = t0 + Ttile;

    const float* base  = x + (size_t)b * Sdim * Cdim + lane * 2;
    float*       obase = y + (size_t)b * Sdim * Cdim + lane * 2;

    const int s0 = t0 - 24;

    // lead invariant entering iter s: sum over [s, s+23]  (= window(s+11))
    // trail invariant entering iter s: sum over [s-24, s-1] (= window(s-13))
    float2 lead  = make_float2(0.f, 0.f);
    float2 trail = make_float2(0.f, 0.f);
#pragma unroll
    for (int i = 0; i < 24; ++i) {
        float2 v = ldx(base, s0 + i);
        lead.x += v.x; lead.y += v.y;
    }
#pragma unroll
    for (int i = 0; i < 24; ++i) {
        float2 v = ldx(base, s0 - 24 + i);
        trail.x += v.x; trail.y += v.y;
    }
    float varsum = 0.f;

#pragma unroll 4
    for (int s = s0; s < t1 + 12; ++s) {
        float2 xa = ldx(base, s + 24);   // fresh row
        float2 xm = ldx(base, s + 12);
        float2 xs = ldx(base, s);
        float2 xb = ldx(base, s - 12);
        float2 xc = ldx(base, s - 24);

        // lead -> window(s+12) = [s+1, s+24]
        lead.x += xa.x - xs.x;
        lead.y += xa.y - xs.y;

        const int p = s + 12;            // sq_tot position being produced
        float st = 0.f;
        if ((unsigned)p < (unsigned)Sdim) {
            const int cnt = min(p + 12, Sdim - 1) - max(p - 11, 0) + 1;
            const float invc = __builtin_amdgcn_rcpf((float)cnt);
            const float dx = xm.x - lead.x * invc;
            const float dy = xm.y - lead.y * invc;
            st = dx * dx + dy * dy;
        }
        st = wave_sum(st);               // full 128-channel sum, all lanes

        // variance window for output q = s-12: add sq_tot(s), sub sq_tot(s-24)
        const float addv = ring[w][s & 63];          // written 12 iters ago
        const float subv = ring[w][(s - 24) & 63];   // written 36 iters ago
        if (lane == 0) ring[w][p & 63] = st;
        varsum += addv - subv;

        // trail -> window(s-12) = [s-23, s]
        trail.x += xs.x - xc.x;
        trail.y += xs.y - xc.y;

        const int q = s - 12;
        if (q >= t0) {                   // q < t1 <= S always holds here
            const int cq = min(q + 12, Sdim - 1) - max(q - 11, 0) + 1;
            const float invq = __builtin_amdgcn_rcpf((float)cq);
            const float stdv = sqrtf(fmaxf(varsum, 0.f) * (1.f / 23.f));
            const float inv  = __builtin_amdgcn_rcpf(stdv + EPSv);
            float2 o;
            o.x = (xb.x - trail.x * invq) * inv;
            o.y = (xb.y - trail.y * invq) * inv;
            *reinterpret_cast<float2*>(obase + (size_t)q * Cdim) = o;
        }
    }
}

extern "C" void kernel_launch(void* const* d_in, const int* in_sizes, int n_in,
                              void* d_out, int out_size, void* d_ws, size_t ws_size,
                              hipStream_t stream) {
    const float* x = (const float*)d_in[0];
    float* y = (float*)d_out;
    // 4096 wave-tiles (32 batches x 128 tiles), 4 waves per 256-thread block
    mzs_kernel<<<dim3(1024), dim3(256), 0, stream>>>(x, y);
}

// Round 2
// 69.862 us; speedup vs baseline: 2.6248x; 2.6248x over previous
//
#include <hip/hip_runtime.h>
#include <math.h>

// MovingZScoreNorm: x[32,8192,128] f32, W=24.
// mean: TF SAME avg-pool with valid-count; var: windowed sum of channel-summed
// sq / (W-1); out = (x-mean)/(sqrt(var)+eps).
//
// One wave per (batch, 128-row tile); lane owns 2 channels (float2).
// Single global load per iteration: x(s+24). All delayed rows live in a
// 36-row register delay line (3 rotating banks x 12, static indexing via
// unrolled chunks). Output mean = lead window-sum delayed 12 iters (register
// bank). sq_tot 24-delay in 3 rotating register banks. No LDS storage.

constexpr int Sdim = 8192;
constexpr int Cdim = 128;
constexpr int TT   = 128;            // output rows per wave
constexpr int NTb  = Sdim / TT;      // 64 tiles per batch
constexpr float EPSv = 1e-7f;

__device__ __forceinline__ float wsum(float v) {
#pragma unroll
    for (int m = 1; m < 64; m <<= 1) v += __shfl_xor(v, m, 64);
    return v;
}

template<bool EDGE>
__device__ __forceinline__ float2 ldg(const float* __restrict__ base, int r) {
    if (EDGE && (unsigned)r >= (unsigned)Sdim) return make_float2(0.f, 0.f);
    return *reinterpret_cast<const float2*>(base + (size_t)r * Cdim);
}

// One chunk of 12 iterations s = cb..cb+11.
// Xw[j] holds x(s-12) (read, then overwritten with fresh x(s+24));
// Xm[j] holds x(s); Xn[j] holds x(s+12).
// Tw[j] <- sq_tot(s); Tr[j] gives sq_tot(s-24).
// Lb[j]: read winsum(s-12), write winsum(s)  (12-delay).
template<bool EDGE, bool LOAD>
__device__ __forceinline__ void chunk12(
    const float* __restrict__ base, float* __restrict__ obase,
    float2 (&Xw)[12], float2 (&Xm)[12], float2 (&Xn)[12],
    float (&Tw)[12], float (&Tr)[12], float2 (&Lb)[12],
    float2& lead, float& varsum, int cb, int t0)
{
#pragma unroll
    for (int j = 0; j < 12; ++j) {
        const int s = cb + j;
        const float2 xold = Xw[j];                 // x(s-12)
        if (LOAD) Xw[j] = ldg<EDGE>(base, s + 24); // consumed 12 iters later
        const float2 xmid = Xn[j];                 // x(s+12)
        lead.x += xmid.x - xold.x;                 // lead -> winsum(s)
        lead.y += xmid.y - xold.y;
        const float2 xcur = Xm[j];                 // x(s)
        float invc;
        if (EDGE) {
            const int cnt = min(s + 12, Sdim - 1) - max(s - 11, 0) + 1;
            invc = __builtin_amdgcn_rcpf((float)cnt);
        } else {
            invc = 1.f / 24.f;
        }
        const float dx = xcur.x - lead.x * invc;
        const float dy = xcur.y - lead.y * invc;
        float st = dx * dx + dy * dy;
        if (EDGE && (unsigned)s >= (unsigned)Sdim) st = 0.f;  // zero-pad sq
        st = wsum(st);                             // 128-ch sq_tot(s)
        varsum += st - Tr[j];                      // -> sum sq_tot[s-23..s]
        Tw[j] = st;
        const float2 wq = Lb[j];                   // winsum(q), q = s-12
        Lb[j] = lead;
        const int q = s - 12;
        if (q >= t0 && q < t0 + TT) {
            float invq;
            if (EDGE) {
                const int cq = min(q + 12, Sdim - 1) - max(q - 11, 0) + 1;
                invq = __builtin_amdgcn_rcpf((float)cq);
            } else {
                invq = 1.f / 24.f;
            }
            const float istd = __builtin_amdgcn_rcpf(
                sqrtf(fmaxf(varsum, 0.f) * (1.f / 23.f)) + EPSv);
            float2 o;
            o.x = (xold.x - wq.x * invq) * istd;
            o.y = (xold.y - wq.y * invq) * istd;
            *reinterpret_cast<float2*>(obase + (size_t)q * Cdim) = o;
        }
    }
}

template<bool EDGE>
__device__ __forceinline__ void run_tile(
    const float* __restrict__ base, float* __restrict__ obase, int t0)
{
    float2 X0[12], X1[12], X2[12], Lb[12];
    float  T0[12], T1[12], T2[12];
    float2 lead = make_float2(0.f, 0.f);
    float  varsum = 0.f;

    // Preload: X0 = x(t0-24+j), X1 = x(t0-12+j), X2 = x(t0+j);
    // lead = winsum(t0-13) = sum x[t0-24 .. t0-1] = sum(X0+X1).
#pragma unroll
    for (int j = 0; j < 12; ++j) {
        X0[j] = ldg<EDGE>(base, t0 - 24 + j);
        X1[j] = ldg<EDGE>(base, t0 - 12 + j);
        X2[j] = ldg<EDGE>(base, t0 + j);
        T0[j] = 0.f; T1[j] = 0.f; T2[j] = 0.f;
        Lb[j] = make_float2(0.f, 0.f);
        lead.x += X0[j].x + X1[j].x;
        lead.y += X0[j].y + X1[j].y;
    }

    // 13 chunks of 12: s = t0-12 .. t0+143 (outputs q = t0 .. t0+127).
    int cb = t0 - 12;
    for (int k = 0; k < 4; ++k) {   // 3-chunk rotation, statically indexed
        chunk12<EDGE, true>(base, obase, X0, X1, X2, T0, T1, Lb, lead, varsum, cb, t0); cb += 12;
        chunk12<EDGE, true>(base, obase, X1, X2, X0, T1, T2, Lb, lead, varsum, cb, t0); cb += 12;
        chunk12<EDGE, true>(base, obase, X2, X0, X1, T2, T0, Lb, lead, varsum, cb, t0); cb += 12;
    }
    chunk12<EDGE, false>(base, obase, X0, X1, X2, T0, T1, Lb, lead, varsum, cb, t0);
}

__global__ __launch_bounds__(256, 2)
void mzs_kernel(const float* __restrict__ x, float* __restrict__ y) {
    const int tid  = threadIdx.x;
    const int lane = tid & 63;
    const int wid  = blockIdx.x * 4 + (tid >> 6);   // 2048 waves
    const int b    = wid >> 6;                      // 64 tiles per batch
    const int ti   = wid & 63;
    const int t0   = ti * TT;
    const float* base  = x + (size_t)b * Sdim * Cdim + lane * 2;
    float*       obase = y + (size_t)b * Sdim * Cdim + lane * 2;
    if (ti == 0 || ti == NTb - 1) run_tile<true >(base, obase, t0);
    else                          run_tile<false>(base, obase, t0);
}

extern "C" void kernel_launch(void* const* d_in, const int* in_sizes, int n_in,
                              void* d_out, int out_size, void* d_ws, size_t ws_size,
                              hipStream_t stream) {
    const float* x = (const float*)d_in[0];
    float* y = (float*)d_out;
    // 2048 wave-tiles (32 batches x 64 tiles), 4 waves per 256-thread block
    mzs_kernel<<<dim3(512), dim3(256), 0, stream>>>(x, y);
}